// Round 6
// baseline (69.574 us; speedup 1.0000x reference)
//
#include <hip/hip_runtime.h>

typedef __attribute__((ext_vector_type(8))) short short8;
typedef __attribute__((ext_vector_type(4))) float f32x4;

#define NB_H 96
#define NB_W 128
#define NB_D 32
#define NB_C 16
#define NB_F 16
#define NPIX (2 * NB_H * NB_W)                 // 24576
#define IMG_ELEMS (NPIX * NB_D * NB_C)         // 12,582,912
#define DV_U16 512
#define KB2_U16 (14 * 512)                     // 7168
#define WS_NEED ((size_t)(IMG_ELEMS + DV_U16 + KB2_U16) * 2)

// fp32 -> bf16 round-to-nearest-even
static __device__ __forceinline__ unsigned short f2bf(float f) {
  unsigned int u = __builtin_bit_cast(unsigned int, f);
  unsigned int r = (u + 0x7fffu + ((u >> 16) & 1u)) >> 16;
  return (unsigned short)r;
}

// Pair table: p=3q+m (q=0..3): m=0 -> taps(6q,6q+1); m=1 -> (6q+3,6q+4);
// m=2 -> (6q+2,6q+5). p=12 -> (24,25). p=13 -> (26, pad).
// tap t = n*3 + kd, neighbor n = (di+1)*3 + (dj+1).

// ---------------- pre-pass: image->bf16, dv page, kernel->B-frag layout ----
__global__ __launch_bounds__(256) void sconv3d_prepass(
    const float* __restrict__ img, const float* __restrict__ kern,
    const float* __restrict__ dvp, unsigned short* __restrict__ wsb) {
  if (blockIdx.x < IMG_ELEMS / (256 * 8)) {
    const int i = (blockIdx.x * 256 + threadIdx.x) * 8;
    const float4 x = *(const float4*)(img + i);
    const float4 y = *(const float4*)(img + i + 4);
    short8 o;
    o[0] = (short)f2bf(x.x); o[1] = (short)f2bf(x.y);
    o[2] = (short)f2bf(x.z); o[3] = (short)f2bf(x.w);
    o[4] = (short)f2bf(y.x); o[5] = (short)f2bf(y.y);
    o[6] = (short)f2bf(y.z); o[7] = (short)f2bf(y.w);
    *(short8*)(wsb + i) = o;
  } else {
    // default-value page
    const unsigned short dvb = f2bf(dvp[0]);
    unsigned short* dvpg = wsb + IMG_ELEMS;
    for (int i = threadIdx.x; i < DV_U16; i += 256) dvpg[i] = dvb;
    // B-fragment-ordered bf16 weights: kb2[p*512 + f*32 + k]
    unsigned short* kb2 = wsb + IMG_ELEMS + DV_U16;
    for (int i = threadIdx.x; i < KB2_U16; i += 256) {
      const int p = i >> 9;
      const int f = (i >> 5) & 15;
      const int k = i & 31;
      int lo, hi;
      if (p < 12) {
        const int q = p / 3, m = p % 3;
        lo = (m == 0) ? 6 * q : (m == 1) ? 6 * q + 3 : 6 * q + 2;
        hi = (m == 0) ? 6 * q + 1 : (m == 1) ? 6 * q + 4 : 6 * q + 5;
      } else if (p == 12) { lo = 24; hi = 25; }
      else { lo = 26; hi = -1; }
      const int t = (k < 16) ? lo : hi;
      const int c = k & 15;
      kb2[i] = (t >= 0) ? f2bf(kern[(t * 16 + c) * 16 + f]) : (unsigned short)0;
    }
  }
}

// ---------------- main: one wave per pixel, scalar neighbor decode ---------
__global__ __launch_bounds__(256) void sconv3d_mfma_c(
    const unsigned short* __restrict__ imgb, const int* __restrict__ bp,
    const unsigned short* __restrict__ kb2, float* __restrict__ out) {
  const int tid = threadIdx.x;
  const int lane = tid & 63;
  const int r = lane & 15;          // A: d row; B/D: f column
  const int grp = lane >> 4;        // 0..3
  const int vc = (grp & 1) * 16;    // byte offset of this lane's c-slice
  const int halfbit = grp >> 1;     // K half: 0 -> tap lo, 1 -> tap hi
  const int rA = r + halfbit - 1;   // depth row pre-rel for (kd0,kd1) pairs
  const int rX = r + 1;             // depth row pre-rel for kd2 pairs
  const int voff_dv = IMG_ELEMS * 2 + vc;  // dv-page byte offset
  const char* imgB = (const char*)imgb;

  // wave-uniform pixel (scalar chain)
  const int wid = __builtin_amdgcn_readfirstlane((int)(tid >> 6));
  const int pix = blockIdx.x * 4 + wid;
  const int b = pix >= (NB_H * NB_W);
  const int rem = pix - b * (NB_H * NB_W);
  const int h = rem >> 7;           // W = 128
  const int w = rem & (NB_W - 1);
  const int bpc = bp[pix];

  f32x4 acc0 = {0.f, 0.f, 0.f, 0.f};  // d = 0..15
  f32x4 acc1 = {0.f, 0.f, 0.f, 0.f};  // d = 16..31

#define CALCN(DI, DJ, SV, BASE, REL)                                   \
  {                                                                    \
    const int hh = h + (DI), ww = w + (DJ);                            \
    SV = (hh >= 0) & (hh < NB_H) & (ww >= 0) & (ww < NB_W);            \
    const int hc = min(max(hh, 0), NB_H - 1);                          \
    const int wc = min(max(ww, 0), NB_W - 1);                          \
    const int nidx = (b * NB_H + hc) * NB_W + wc;                      \
    REL = bpc - bp[nidx];                                              \
    BASE = nidx << 10; /* *NB_D*NB_C*2 bytes */                        \
  }

#define PAIR_UNIF(P, SV, BASE, REL)                                    \
  {                                                                    \
    const short8 bf = *(const short8*)(kb2 + (P) * 512 + r * 32 + grp * 8); \
    const int ds0 = rA + (REL);                                        \
    int vo0 = (BASE) + (ds0 << 5) + vc;                                \
    vo0 = ((SV) && (unsigned)ds0 < NB_D) ? vo0 : voff_dv;              \
    const short8 a0 = *(const short8*)(imgB + vo0);                    \
    acc0 = __builtin_amdgcn_mfma_f32_16x16x32_bf16(a0, bf, acc0, 0, 0, 0); \
    const int ds1 = ds0 + 16;                                          \
    int vo1 = (BASE) + (ds1 << 5) + vc;                                \
    vo1 = ((SV) && (unsigned)ds1 < NB_D) ? vo1 : voff_dv;              \
    const short8 a1 = *(const short8*)(imgB + vo1);                    \
    acc1 = __builtin_amdgcn_mfma_f32_16x16x32_bf16(a1, bf, acc1, 0, 0, 0); \
  }

#define PAIR_MIX(P, SVE, BASEE, RELE, SVO, BASEO, RELO)                \
  {                                                                    \
    const short8 bf = *(const short8*)(kb2 + (P) * 512 + r * 32 + grp * 8); \
    const int relS = halfbit ? (RELO) : (RELE);                        \
    const int baseS = halfbit ? (BASEO) : (BASEE);                     \
    const int svS = halfbit ? (SVO) : (SVE);                           \
    const int ds0 = rX + relS;                                         \
    int vo0 = baseS + (ds0 << 5) + vc;                                 \
    vo0 = (svS && (unsigned)ds0 < NB_D) ? vo0 : voff_dv;               \
    const short8 a0 = *(const short8*)(imgB + vo0);                    \
    acc0 = __builtin_amdgcn_mfma_f32_16x16x32_bf16(a0, bf, acc0, 0, 0, 0); \
    const int ds1 = ds0 + 16;                                          \
    int vo1 = baseS + (ds1 << 5) + vc;                                 \
    vo1 = (svS && (unsigned)ds1 < NB_D) ? vo1 : voff_dv;               \
    const short8 a1 = *(const short8*)(imgB + vo1);                    \
    acc1 = __builtin_amdgcn_mfma_f32_16x16x32_bf16(a1, bf, acc1, 0, 0, 0); \
  }

  int svA, baseA, relA, svB, baseB, relB;

  // q=0: n0(-1,-1), n1(-1,0)
  CALCN(-1, -1, svA, baseA, relA);
  CALCN(-1, 0, svB, baseB, relB);
  PAIR_UNIF(0, svA, baseA, relA);
  PAIR_UNIF(1, svB, baseB, relB);
  PAIR_MIX(2, svA, baseA, relA, svB, baseB, relB);
  // q=1: n2(-1,+1), n3(0,-1)
  CALCN(-1, 1, svA, baseA, relA);
  CALCN(0, -1, svB, baseB, relB);
  PAIR_UNIF(3, svA, baseA, relA);
  PAIR_UNIF(4, svB, baseB, relB);
  PAIR_MIX(5, svA, baseA, relA, svB, baseB, relB);
  // q=2: n4(0,0), n5(0,+1)
  CALCN(0, 0, svA, baseA, relA);
  CALCN(0, 1, svB, baseB, relB);
  PAIR_UNIF(6, svA, baseA, relA);
  PAIR_UNIF(7, svB, baseB, relB);
  PAIR_MIX(8, svA, baseA, relA, svB, baseB, relB);
  // q=3: n6(+1,-1), n7(+1,0)
  CALCN(1, -1, svA, baseA, relA);
  CALCN(1, 0, svB, baseB, relB);
  PAIR_UNIF(9, svA, baseA, relA);
  PAIR_UNIF(10, svB, baseB, relB);
  PAIR_MIX(11, svA, baseA, relA, svB, baseB, relB);
  // n8(+1,+1): pair 12 = (kd0,kd1), pair 13 = (kd2, pad)
  CALCN(1, 1, svA, baseA, relA);
  PAIR_UNIF(12, svA, baseA, relA);
  PAIR_MIX(13, svA, baseA, relA, 0, baseA, relA);

#undef CALCN
#undef PAIR_UNIF
#undef PAIR_MIX

  // D layout: col = lane&15 (=f), row = grp*4 + reg
  const int obase = pix * (NB_D * NB_F);
#pragma unroll
  for (int rr = 0; rr < 4; ++rr) {
    out[obase + (grp * 4 + rr) * NB_F + r] = acc0[rr];
    out[obase + (grp * 4 + rr + 16) * NB_F + r] = acc1[rr];
  }
}

// ---------------- fallback (round-2 kernel) if ws is too small -------------
__global__ __launch_bounds__(256) void sconv3d_mfma(
    const float* __restrict__ img, const int* __restrict__ bp,
    const float* __restrict__ kern, const float* __restrict__ dvp,
    float* __restrict__ out, int npix) {
  __shared__ unsigned short Kb[28 * 256];
  const int tid = threadIdx.x;
  for (int idx = tid; idx < 28 * 256; idx += 256) {
    unsigned short v = 0;
    if (idx < 27 * 256) v = f2bf(kern[idx]);
    Kb[idx] = v;
  }
  __syncthreads();

  const int lane = tid & 63;
  const int grp = lane >> 4;
  const int r = lane & 15;
  const int c0 = (grp & 1) * 8;
  const int half = grp >> 1;

  short8 bfrag[14];
#pragma unroll
  for (int p = 0; p < 14; ++p) {
#pragma unroll
    for (int j = 0; j < 8; ++j) {
      const int k = 8 * grp + j;
      const int t = 2 * p + (k >> 4);
      bfrag[p][j] = (short)Kb[t * 256 + (k & 15) * 16 + r];
    }
  }

  const int pix = blockIdx.x * 4 + (tid >> 6);
  if (pix >= npix) return;
  const int b = pix / (NB_H * NB_W);
  const int rem = pix - b * (NB_H * NB_W);
  const int h = rem >> 7;
  const int w = rem & (NB_W - 1);

  const float dv = dvp[0];
  const int bpc = bp[pix];

  f32x4 acc0 = {0.f, 0.f, 0.f, 0.f};
  f32x4 acc1 = {0.f, 0.f, 0.f, 0.f};

#pragma unroll
  for (int p = 0; p < 14; ++p) {
    const int t = 2 * p + half;
    const int n = t / 3;
    const int kd = t - 3 * n;
    const int i = n / 3;
    const int j = n - 3 * i;
    const int hh = h + i - 1;
    const int ww = w + j - 1;
    const bool sv =
        (t < 27) && (hh >= 0) && (hh < NB_H) && (ww >= 0) && (ww < NB_W);
    const int hc = min(max(hh, 0), NB_H - 1);
    const int wc = min(max(ww, 0), NB_W - 1);
    const int nidx = (b * NB_H + hc) * NB_W + wc;
    const int rel = bpc - bp[nidx];
    const int base = nidx * (NB_D * NB_C);
    const int dsh = (kd - 1) + rel;

    const int ds0 = r + dsh;
    short8 a0;
    {
      float va[8];
      if (sv && (ds0 >= 0) && (ds0 < NB_D)) {
        const float4* pp = (const float4*)(img + base + ds0 * NB_C + c0);
        const float4 x = pp[0];
        const float4 y = pp[1];
        va[0] = x.x; va[1] = x.y; va[2] = x.z; va[3] = x.w;
        va[4] = y.x; va[5] = y.y; va[6] = y.z; va[7] = y.w;
      } else {
#pragma unroll
        for (int q = 0; q < 8; ++q) va[q] = dv;
      }
#pragma unroll
      for (int q = 0; q < 8; ++q) a0[q] = (short)f2bf(va[q]);
    }
    acc0 = __builtin_amdgcn_mfma_f32_16x16x32_bf16(a0, bfrag[p], acc0, 0, 0, 0);

    const int ds1 = ds0 + 16;
    short8 a1;
    {
      float va[8];
      if (sv && (ds1 >= 0) && (ds1 < NB_D)) {
        const float4* pp = (const float4*)(img + base + ds1 * NB_C + c0);
        const float4 x = pp[0];
        const float4 y = pp[1];
        va[0] = x.x; va[1] = x.y; va[2] = x.z; va[3] = x.w;
        va[4] = y.x; va[5] = y.y; va[6] = y.z; va[7] = y.w;
      } else {
#pragma unroll
        for (int q = 0; q < 8; ++q) va[q] = dv;
      }
#pragma unroll
      for (int q = 0; q < 8; ++q) a1[q] = (short)f2bf(va[q]);
    }
    acc1 = __builtin_amdgcn_mfma_f32_16x16x32_bf16(a1, bfrag[p], acc1, 0, 0, 0);
  }

  const int obase = pix * (NB_D * NB_F);
#pragma unroll
  for (int rr = 0; rr < 4; ++rr) {
    out[obase + (grp * 4 + rr) * NB_F + r] = acc0[rr];
    out[obase + (grp * 4 + rr + 16) * NB_F + r] = acc1[rr];
  }
}

extern "C" void kernel_launch(void* const* d_in, const int* in_sizes, int n_in,
                              void* d_out, int out_size, void* d_ws, size_t ws_size,
                              hipStream_t stream) {
  const float* img = (const float*)d_in[0];
  const int* bp = (const int*)d_in[1];
  const float* kern = (const float*)d_in[2];
  const float* dvp = (const float*)d_in[3];
  float* out = (float*)d_out;

  if (ws_size >= WS_NEED) {
    unsigned short* wsb = (unsigned short*)d_ws;
    const int img_blocks = IMG_ELEMS / (256 * 8);   // 6144
    sconv3d_prepass<<<img_blocks + 1, 256, 0, stream>>>(img, kern, dvp, wsb);
    sconv3d_mfma_c<<<NPIX / 4, 256, 0, stream>>>(
        wsb, bp, wsb + IMG_ELEMS + DV_U16, out);
  } else {
    sconv3d_mfma<<<NPIX / 4, 256, 0, stream>>>(img, bp, kern, dvp, out, NPIX);
  }
}

// Round 7
// 55.492 us; speedup vs baseline: 1.2538x; 1.2538x over previous
//
#include <hip/hip_runtime.h>

typedef __attribute__((ext_vector_type(8))) short short8;
typedef __attribute__((ext_vector_type(4))) float f32x4;

#define NB_H 96
#define NB_W 128
#define NB_D 32
#define NB_C 16
#define NB_F 16
#define NPIX (2 * NB_H * NB_W)                 // 24576
#define IMG_ELEMS (NPIX * NB_D * NB_C)         // 12,582,912
#define DV_U16 512
#define KB2_U16 (14 * 512)                     // 7168
#define WS_NEED ((size_t)(IMG_ELEMS + DV_U16 + KB2_U16) * 2)

// fp32 -> bf16 round-to-nearest-even
static __device__ __forceinline__ unsigned short f2bf(float f) {
  unsigned int u = __builtin_bit_cast(unsigned int, f);
  unsigned int r = (u + 0x7fffu + ((u >> 16) & 1u)) >> 16;
  return (unsigned short)r;
}

// Pair table: p=3q+m (q=0..3): m=0 -> taps(6q,6q+1) [UNIF n=2q, kd=0/1];
// m=1 -> (6q+3,6q+4) [UNIF n=2q+1]; m=2 -> (6q+2,6q+5) [MIX kd=2, n=2q/2q+1].
// p=12 -> (24,25) [UNIF n=8]. p=13 -> (26,pad) [MIX n=8, odd=pad].

// ---------------- pre-pass: image->bf16, dv page, kernel->B-frag layout ----
__global__ __launch_bounds__(256) void sconv3d_prepass(
    const float* __restrict__ img, const float* __restrict__ kern,
    const float* __restrict__ dvp, unsigned short* __restrict__ wsb) {
  if (blockIdx.x < IMG_ELEMS / (256 * 8)) {
    const int i = (blockIdx.x * 256 + threadIdx.x) * 8;
    const float4 x = *(const float4*)(img + i);
    const float4 y = *(const float4*)(img + i + 4);
    short8 o;
    o[0] = (short)f2bf(x.x); o[1] = (short)f2bf(x.y);
    o[2] = (short)f2bf(x.z); o[3] = (short)f2bf(x.w);
    o[4] = (short)f2bf(y.x); o[5] = (short)f2bf(y.y);
    o[6] = (short)f2bf(y.z); o[7] = (short)f2bf(y.w);
    *(short8*)(wsb + i) = o;
  } else {
    const unsigned short dvb = f2bf(dvp[0]);
    unsigned short* dvpg = wsb + IMG_ELEMS;
    for (int i = threadIdx.x; i < DV_U16; i += 256) dvpg[i] = dvb;
    unsigned short* kb2 = wsb + IMG_ELEMS + DV_U16;
    for (int i = threadIdx.x; i < KB2_U16; i += 256) {
      const int p = i >> 9;
      const int f = (i >> 5) & 15;
      const int k = i & 31;
      int lo, hi;
      if (p < 12) {
        const int q = p / 3, m = p % 3;
        lo = (m == 0) ? 6 * q : (m == 1) ? 6 * q + 3 : 6 * q + 2;
        hi = (m == 0) ? 6 * q + 1 : (m == 1) ? 6 * q + 4 : 6 * q + 5;
      } else if (p == 12) { lo = 24; hi = 25; }
      else { lo = 26; hi = -1; }
      const int t = (k < 16) ? lo : hi;
      const int c = k & 15;
      kb2[i] = (t >= 0) ? f2bf(kern[(t * 16 + c) * 16 + f]) : (unsigned short)0;
    }
  }
}

// ------- main: one wave/pixel, scalar decode, 4-slot load pipeline ---------
__global__ __launch_bounds__(256, 4) void sconv3d_mfma_d(
    const unsigned short* __restrict__ imgb, const int* __restrict__ bp,
    const unsigned short* __restrict__ kb2, float* __restrict__ out) {
  __shared__ unsigned short KbS[KB2_U16];   // 14336 B, B-frags per pair
  const int tid = threadIdx.x;
  {
    const int4* src = (const int4*)kb2;
    int4* dst = (int4*)KbS;
#pragma unroll
    for (int i = 0; i < 4; ++i) {
      const int idx = tid + i * 256;
      if (idx < KB2_U16 / 8) dst[idx] = src[idx];
    }
  }
  __syncthreads();

  const int lane = tid & 63;
  const int r = lane & 15;          // A: d row; B/D: f column
  const int grp = lane >> 4;        // 0..3
  const int vc = (grp & 1) * 16;    // byte offset of this lane's c-slice
  const int halfbit = grp >> 1;     // K half: 0 -> tap lo, 1 -> tap hi
  const int rA = r + halfbit - 1;   // depth row pre-rel, kd=(0,1) pairs
  const int rX = r + 1;             // depth row pre-rel, kd=2 pairs
  const int voff_dv = IMG_ELEMS * 2 + vc;
  const char* imgB = (const char*)imgb;

  // wave-uniform pixel (scalar chain)
  const int wid = __builtin_amdgcn_readfirstlane((int)(tid >> 6));
  const int pix = blockIdx.x * 4 + wid;
  const int b = pix >= (NB_H * NB_W);
  const int rem = pix - b * (NB_H * NB_W);
  const int h = rem >> 7;           // W = 128
  const int w = rem & (NB_W - 1);
  const int bpc = bp[pix];

#define CALCN(DI, DJ, SV, BASE, REL)                                   \
  {                                                                    \
    const int hh = h + (DI), ww = w + (DJ);                            \
    SV = (hh >= 0) & (hh < NB_H) & (ww >= 0) & (ww < NB_W);            \
    const int hc = min(max(hh, 0), NB_H - 1);                          \
    const int wc = min(max(ww, 0), NB_W - 1);                          \
    const int nidx = (b * NB_H + hc) * NB_W + wc;                      \
    REL = bpc - bp[nidx];                                              \
    BASE = nidx << 10; /* *NB_D*NB_C*2 bytes */                        \
  }

  int sv0, ba0, re0, sv1, ba1, re1, sv2, ba2, re2, sv3, ba3, re3;
  int sv4, ba4, re4, sv5, ba5, re5, sv6, ba6, re6, sv7, ba7, re7;
  int sv8, ba8, re8;
  CALCN(-1, -1, sv0, ba0, re0);
  CALCN(-1, 0, sv1, ba1, re1);
  CALCN(-1, 1, sv2, ba2, re2);
  CALCN(0, -1, sv3, ba3, re3);
  CALCN(0, 0, sv4, ba4, re4);
  CALCN(0, 1, sv5, ba5, re5);
  CALCN(1, -1, sv6, ba6, re6);
  CALCN(1, 0, sv7, ba7, re7);
  CALCN(1, 1, sv8, ba8, re8);
#undef CALCN

  f32x4 acc0 = {0.f, 0.f, 0.f, 0.f};  // d = 0..15
  f32x4 acc1 = {0.f, 0.f, 0.f, 0.f};  // d = 16..31

  short8 sA0, sB0, sA1, sB1, sA2, sB2, sA3, sB3;  // 4 slots x 2 d-tiles

#define ISSUE_U(AV, BV, SV, BA, RE)                                    \
  {                                                                    \
    const int ds0 = rA + (RE);                                         \
    int vo0 = (BA) + (ds0 << 5) + vc;                                  \
    vo0 = ((SV) && (unsigned)ds0 < NB_D) ? vo0 : voff_dv;              \
    AV = *(const short8*)(imgB + vo0);                                 \
    const int ds1 = ds0 + 16;                                          \
    int vo1 = (BA) + (ds1 << 5) + vc;                                  \
    vo1 = ((SV) && (unsigned)ds1 < NB_D) ? vo1 : voff_dv;              \
    BV = *(const short8*)(imgB + vo1);                                 \
  }

#define ISSUE_M(AV, BV, SVE, BAE, REE, SVO, BAO, REO)                  \
  {                                                                    \
    const int relS = halfbit ? (REO) : (REE);                          \
    const int baS = halfbit ? (BAO) : (BAE);                           \
    const int svS = halfbit ? (SVO) : (SVE);                           \
    const int ds0 = rX + relS;                                         \
    int vo0 = baS + (ds0 << 5) + vc;                                   \
    vo0 = (svS && (unsigned)ds0 < NB_D) ? vo0 : voff_dv;               \
    AV = *(const short8*)(imgB + vo0);                                 \
    const int ds1 = ds0 + 16;                                          \
    int vo1 = baS + (ds1 << 5) + vc;                                   \
    vo1 = (svS && (unsigned)ds1 < NB_D) ? vo1 : voff_dv;               \
    BV = *(const short8*)(imgB + vo1);                                 \
  }

#define FMA_P(P, AV, BV)                                               \
  {                                                                    \
    const short8 bf = *(const short8*)(KbS + (P) * 512 + r * 32 + grp * 8); \
    acc0 = __builtin_amdgcn_mfma_f32_16x16x32_bf16(AV, bf, acc0, 0, 0, 0);  \
    acc1 = __builtin_amdgcn_mfma_f32_16x16x32_bf16(BV, bf, acc1, 0, 0, 0);  \
  }

  // prologue: fill 4 slots (8 loads in flight)
  ISSUE_U(sA0, sB0, sv0, ba0, re0);                     // p0
  ISSUE_U(sA1, sB1, sv1, ba1, re1);                     // p1
  ISSUE_M(sA2, sB2, sv0, ba0, re0, sv1, ba1, re1);      // p2
  ISSUE_U(sA3, sB3, sv2, ba2, re2);                     // p3
  // steady state: consume slot, refill with pair p+4
  FMA_P(0, sA0, sB0); ISSUE_U(sA0, sB0, sv3, ba3, re3);                // p4
  FMA_P(1, sA1, sB1); ISSUE_M(sA1, sB1, sv2, ba2, re2, sv3, ba3, re3); // p5
  FMA_P(2, sA2, sB2); ISSUE_U(sA2, sB2, sv4, ba4, re4);                // p6
  FMA_P(3, sA3, sB3); ISSUE_U(sA3, sB3, sv5, ba5, re5);                // p7
  FMA_P(4, sA0, sB0); ISSUE_M(sA0, sB0, sv4, ba4, re4, sv5, ba5, re5); // p8
  FMA_P(5, sA1, sB1); ISSUE_U(sA1, sB1, sv6, ba6, re6);                // p9
  FMA_P(6, sA2, sB2); ISSUE_U(sA2, sB2, sv7, ba7, re7);                // p10
  FMA_P(7, sA3, sB3); ISSUE_M(sA3, sB3, sv6, ba6, re6, sv7, ba7, re7); // p11
  FMA_P(8, sA0, sB0); ISSUE_U(sA0, sB0, sv8, ba8, re8);                // p12
  FMA_P(9, sA1, sB1); ISSUE_M(sA1, sB1, sv8, ba8, re8, 0, ba8, re8);   // p13
  // epilogue
  FMA_P(10, sA2, sB2);
  FMA_P(11, sA3, sB3);
  FMA_P(12, sA0, sB0);
  FMA_P(13, sA1, sB1);

#undef ISSUE_U
#undef ISSUE_M
#undef FMA_P

  // D layout: col = lane&15 (=f), row = grp*4 + reg
  const int obase = pix * (NB_D * NB_F);
#pragma unroll
  for (int rr = 0; rr < 4; ++rr) {
    out[obase + (grp * 4 + rr) * NB_F + r] = acc0[rr];
    out[obase + (grp * 4 + rr + 16) * NB_F + r] = acc1[rr];
  }
}

// ---------------- fallback (round-2 kernel) if ws is too small -------------
__global__ __launch_bounds__(256) void sconv3d_mfma(
    const float* __restrict__ img, const int* __restrict__ bp,
    const float* __restrict__ kern, const float* __restrict__ dvp,
    float* __restrict__ out, int npix) {
  __shared__ unsigned short Kb[28 * 256];
  const int tid = threadIdx.x;
  for (int idx = tid; idx < 28 * 256; idx += 256) {
    unsigned short v = 0;
    if (idx < 27 * 256) v = f2bf(kern[idx]);
    Kb[idx] = v;
  }
  __syncthreads();

  const int lane = tid & 63;
  const int grp = lane >> 4;
  const int r = lane & 15;
  const int c0 = (grp & 1) * 8;
  const int half = grp >> 1;

  short8 bfrag[14];
#pragma unroll
  for (int p = 0; p < 14; ++p) {
#pragma unroll
    for (int j = 0; j < 8; ++j) {
      const int k = 8 * grp + j;
      const int t = 2 * p + (k >> 4);
      bfrag[p][j] = (short)Kb[t * 256 + (k & 15) * 16 + r];
    }
  }

  const int pix = blockIdx.x * 4 + (tid >> 6);
  if (pix >= npix) return;
  const int b = pix / (NB_H * NB_W);
  const int rem = pix - b * (NB_H * NB_W);
  const int h = rem >> 7;
  const int w = rem & (NB_W - 1);

  const float dv = dvp[0];
  const int bpc = bp[pix];

  f32x4 acc0 = {0.f, 0.f, 0.f, 0.f};
  f32x4 acc1 = {0.f, 0.f, 0.f, 0.f};

#pragma unroll
  for (int p = 0; p < 14; ++p) {
    const int t = 2 * p + half;
    const int n = t / 3;
    const int kd = t - 3 * n;
    const int i = n / 3;
    const int j = n - 3 * i;
    const int hh = h + i - 1;
    const int ww = w + j - 1;
    const bool sv =
        (t < 27) && (hh >= 0) && (hh < NB_H) && (ww >= 0) && (ww < NB_W);
    const int hc = min(max(hh, 0), NB_H - 1);
    const int wc = min(max(ww, 0), NB_W - 1);
    const int nidx = (b * NB_H + hc) * NB_W + wc;
    const int rel = bpc - bp[nidx];
    const int base = nidx * (NB_D * NB_C);
    const int dsh = (kd - 1) + rel;

    const int ds0 = r + dsh;
    short8 a0;
    {
      float va[8];
      if (sv && (ds0 >= 0) && (ds0 < NB_D)) {
        const float4* pp = (const float4*)(img + base + ds0 * NB_C + c0);
        const float4 x = pp[0];
        const float4 y = pp[1];
        va[0] = x.x; va[1] = x.y; va[2] = x.z; va[3] = x.w;
        va[4] = y.x; va[5] = y.y; va[6] = y.z; va[7] = y.w;
      } else {
#pragma unroll
        for (int q = 0; q < 8; ++q) va[q] = dv;
      }
#pragma unroll
      for (int q = 0; q < 8; ++q) a0[q] = (short)f2bf(va[q]);
    }
    acc0 = __builtin_amdgcn_mfma_f32_16x16x32_bf16(a0, bfrag[p], acc0, 0, 0, 0);

    const int ds1 = ds0 + 16;
    short8 a1;
    {
      float va[8];
      if (sv && (ds1 >= 0) && (ds1 < NB_D)) {
        const float4* pp = (const float4*)(img + base + ds1 * NB_C + c0);
        const float4 x = pp[0];
        const float4 y = pp[1];
        va[0] = x.x; va[1] = x.y; va[2] = x.z; va[3] = x.w;
        va[4] = y.x; va[5] = y.y; va[6] = y.z; va[7] = y.w;
      } else {
#pragma unroll
        for (int q = 0; q < 8; ++q) va[q] = dv;
      }
#pragma unroll
      for (int q = 0; q < 8; ++q) a1[q] = (short)f2bf(va[q]);
    }
    acc1 = __builtin_amdgcn_mfma_f32_16x16x32_bf16(a1, bfrag[p], acc1, 0, 0, 0);
  }

  const int obase = pix * (NB_D * NB_F);
#pragma unroll
  for (int rr = 0; rr < 4; ++rr) {
    out[obase + (grp * 4 + rr) * NB_F + r] = acc0[rr];
    out[obase + (grp * 4 + rr + 16) * NB_F + r] = acc1[rr];
  }
}

extern "C" void kernel_launch(void* const* d_in, const int* in_sizes, int n_in,
                              void* d_out, int out_size, void* d_ws, size_t ws_size,
                              hipStream_t stream) {
  const float* img = (const float*)d_in[0];
  const int* bp = (const int*)d_in[1];
  const float* kern = (const float*)d_in[2];
  const float* dvp = (const float*)d_in[3];
  float* out = (float*)d_out;

  if (ws_size >= WS_NEED) {
    unsigned short* wsb = (unsigned short*)d_ws;
    const int img_blocks = IMG_ELEMS / (256 * 8);   // 6144
    sconv3d_prepass<<<img_blocks + 1, 256, 0, stream>>>(img, kern, dvp, wsb);
    sconv3d_mfma_d<<<NPIX / 4, 256, 0, stream>>>(
        wsb, bp, wsb + IMG_ELEMS + DV_U16, out);
  } else {
    sconv3d_mfma<<<NPIX / 4, 256, 0, stream>>>(img, bp, kern, dvp, out, NPIX);
  }
}

// Round 8
// 43.059 us; speedup vs baseline: 1.6158x; 1.2887x over previous
//
#include <hip/hip_runtime.h>

typedef __attribute__((ext_vector_type(8))) short short8;
typedef __attribute__((ext_vector_type(4))) short s16x4;
typedef __attribute__((ext_vector_type(4))) float f32x4;

#define NB_H 96
#define NB_W 128
#define NB_D 32
#define NB_C 16
#define NB_F 16
#define NPIX (2 * NB_H * NB_W)                 // 24576
#define KB2_U16 (14 * 512)                     // 7168 u16 = 14336 B
#define WS_NEED ((size_t)KB2_U16 * 2)
#define SLAB_STRIDE 1536                       // 32 rows * 48 B (32 data + 16 pad)
#define NSLAB 18                               // 3h x 6w
#define DV_OFF (NSLAB * SLAB_STRIDE)           // dv slab byte offset

// fp32 -> bf16 round-to-nearest-even
static __device__ __forceinline__ unsigned short f2bf(float f) {
  unsigned int u = __builtin_bit_cast(unsigned int, f);
  unsigned int r = (u + 0x7fffu + ((u >> 16) & 1u)) >> 16;
  return (unsigned short)r;
}

// Pair table: p=3q+m (q=0..3): m=0 -> taps(6q,6q+1) [UNIF n=2q, kd=0/1];
// m=1 -> (6q+3,6q+4) [UNIF n=2q+1]; m=2 -> (6q+2,6q+5) [MIX kd=2].
// p=12 -> (24,25) [UNIF n=8]. p=13 -> (26,pad). tap t = n*3+kd.

// ---- weights prep: kern fp32 -> bf16 B-fragment layout in d_ws ------------
__global__ __launch_bounds__(256) void sconv3d_wprep(
    const float* __restrict__ kern, unsigned short* __restrict__ kb2) {
  const int i = blockIdx.x * 256 + threadIdx.x;
  if (i >= KB2_U16) return;
  const int p = i >> 9;
  const int f = (i >> 5) & 15;
  const int k = i & 31;
  int lo, hi;
  if (p < 12) {
    const int q = p / 3, m = p % 3;
    lo = (m == 0) ? 6 * q : (m == 1) ? 6 * q + 3 : 6 * q + 2;
    hi = (m == 0) ? 6 * q + 1 : (m == 1) ? 6 * q + 4 : 6 * q + 5;
  } else if (p == 12) { lo = 24; hi = 25; }
  else { lo = 26; hi = -1; }
  const int t = (k < 16) ? lo : hi;
  const int c = k & 15;
  kb2[i] = (t >= 0) ? f2bf(kern[(t * 16 + c) * 16 + f]) : (unsigned short)0;
}

// ---- fused main: stage 18 slabs fp32->bf16 in LDS, MFMA from LDS ----------
__global__ __launch_bounds__(256, 4) void sconv3d_fused(
    const float* __restrict__ img, const int* __restrict__ bp,
    const unsigned short* __restrict__ kb2, const float* __restrict__ dvp,
    float* __restrict__ out) {
  __shared__ unsigned short S[(NSLAB + 1) * SLAB_STRIDE / 2];
  char* Sb = (char*)S;
  const int tid = threadIdx.x;
  const int lane = tid & 63;
  const int r = lane & 15;          // A: d row; B/D: f column
  const int grp = lane >> 4;        // 0..3
  const int vc = (grp & 1) * 16;    // byte offset of c-slice within 32B row
  const int halfbit = grp >> 1;     // K half: 0 -> tap lo, 1 -> tap hi
  const int rA = r + halfbit - 1;   // depth row pre-rel, kd=(0,1) pairs
  const int rX = r + 1;             // depth row pre-rel, kd=2 pairs
  const int voff_dv = DV_OFF + vc;

  // B-fragments: issue early, consumed after sync (latency hides under stage)
  short8 bfrag[14];
#pragma unroll
  for (int p = 0; p < 14; ++p)
    bfrag[p] = *(const short8*)(kb2 + p * 512 + r * 32 + grp * 8);

  // XCD-chunked bijective swizzle: 6144 = 8 * 768
  const int bid = (blockIdx.x & 7) * 768 + (blockIdx.x >> 3);
  const int b = bid / (NB_H * 32);            // 32 blocks per row (W/4)
  const int rem = bid - b * (NB_H * 32);
  const int h = rem >> 5;
  const int wb = (rem & 31) * 4;              // first pixel w of block

  // ---- stage 18 slabs (3h x 6w, clamped coords) fp32 -> bf16 -> LDS ----
  const int t2 = tid & 127;
  const int srow = t2 >> 2;                   // d row 0..31
  const int scq = (t2 & 3) * 4;               // c quad 0,4,8,12
#pragma unroll
  for (int pass = 0; pass < 9; ++pass) {
    const int s = pass * 2 + (tid >> 7);      // slab 0..17
    const int dh = s / 6, col = s - 6 * dh;
    const int hh = min(max(h + dh - 1, 0), NB_H - 1);
    const int ww = min(max(wb + col - 1, 0), NB_W - 1);
    const int nidx = (b * NB_H + hh) * NB_W + ww;
    const float4 v = *(const float4*)(img + nidx * (NB_D * NB_C) + t2 * 4);
    s16x4 o;
    o[0] = (short)f2bf(v.x); o[1] = (short)f2bf(v.y);
    o[2] = (short)f2bf(v.z); o[3] = (short)f2bf(v.w);
    *(s16x4*)(Sb + s * SLAB_STRIDE + srow * 48 + scq * 2) = o;
  }
  // dv slab (only first 32 B are ever read)
  const unsigned short dvb = f2bf(dvp[0]);
  if (tid < 16) S[DV_OFF / 2 + tid] = dvb;

  // ---- per-wave pixel + neighbor decode (overlaps staging stores) ----
  const int wid = __builtin_amdgcn_readfirstlane((int)(tid >> 6));
  const int w = wb + wid;
  const int pix = (b * NB_H + h) * NB_W + w;
  const int bpc = bp[pix];

#define CALCN(DI, DJ, SV, BASE, REL)                                    \
  {                                                                     \
    const int hh = h + (DI), ww = w + (DJ);                             \
    SV = (hh >= 0) & (hh < NB_H) & (ww >= 0) & (ww < NB_W);             \
    const int hc = min(max(hh, 0), NB_H - 1);                           \
    const int wc = min(max(ww, 0), NB_W - 1);                           \
    REL = bpc - bp[(b * NB_H + hc) * NB_W + wc];                        \
    BASE = (((DI) + 1) * 6 + wid + (DJ) + 1) * SLAB_STRIDE;             \
  }

  int sv0, ba0, re0, sv1, ba1, re1, sv2, ba2, re2, sv3, ba3, re3;
  int sv4, ba4, re4, sv5, ba5, re5, sv6, ba6, re6, sv7, ba7, re7;
  int sv8, ba8, re8;
  CALCN(-1, -1, sv0, ba0, re0);
  CALCN(-1, 0, sv1, ba1, re1);
  CALCN(-1, 1, sv2, ba2, re2);
  CALCN(0, -1, sv3, ba3, re3);
  CALCN(0, 0, sv4, ba4, re4);
  CALCN(0, 1, sv5, ba5, re5);
  CALCN(1, -1, sv6, ba6, re6);
  CALCN(1, 0, sv7, ba7, re7);
  CALCN(1, 1, sv8, ba8, re8);
#undef CALCN

  __syncthreads();

  f32x4 acc0 = {0.f, 0.f, 0.f, 0.f};  // d = 0..15
  f32x4 acc1 = {0.f, 0.f, 0.f, 0.f};  // d = 16..31

#define PAIR_UNIF(P, SV, BA, RE)                                        \
  {                                                                     \
    const int ds0 = rA + (RE);                                          \
    int vo0 = (BA) + ds0 * 48 + vc;                                     \
    vo0 = ((SV) && (unsigned)ds0 < NB_D) ? vo0 : voff_dv;               \
    const short8 a0 = *(const short8*)(Sb + vo0);                       \
    acc0 = __builtin_amdgcn_mfma_f32_16x16x32_bf16(a0, bfrag[P], acc0, 0, 0, 0); \
    const int ds1 = ds0 + 16;                                           \
    int vo1 = (BA) + ds1 * 48 + vc;                                     \
    vo1 = ((SV) && (unsigned)ds1 < NB_D) ? vo1 : voff_dv;               \
    const short8 a1 = *(const short8*)(Sb + vo1);                       \
    acc1 = __builtin_amdgcn_mfma_f32_16x16x32_bf16(a1, bfrag[P], acc1, 0, 0, 0); \
  }

#define PAIR_MIX(P, SVE, BAE, REE, SVO, BAO, REO)                       \
  {                                                                     \
    const int relS = halfbit ? (REO) : (REE);                           \
    const int baS = halfbit ? (BAO) : (BAE);                            \
    const int svS = halfbit ? (SVO) : (SVE);                            \
    const int ds0 = rX + relS;                                          \
    int vo0 = baS + ds0 * 48 + vc;                                      \
    vo0 = (svS && (unsigned)ds0 < NB_D) ? vo0 : voff_dv;                \
    const short8 a0 = *(const short8*)(Sb + vo0);                       \
    acc0 = __builtin_amdgcn_mfma_f32_16x16x32_bf16(a0, bfrag[P], acc0, 0, 0, 0); \
    const int ds1 = ds0 + 16;                                           \
    int vo1 = baS + ds1 * 48 + vc;                                      \
    vo1 = (svS && (unsigned)ds1 < NB_D) ? vo1 : voff_dv;                \
    const short8 a1 = *(const short8*)(Sb + vo1);                       \
    acc1 = __builtin_amdgcn_mfma_f32_16x16x32_bf16(a1, bfrag[P], acc1, 0, 0, 0); \
  }

  // q=0: n0(-1,-1), n1(-1,0)
  PAIR_UNIF(0, sv0, ba0, re0);
  PAIR_UNIF(1, sv1, ba1, re1);
  PAIR_MIX(2, sv0, ba0, re0, sv1, ba1, re1);
  // q=1: n2(-1,+1), n3(0,-1)
  PAIR_UNIF(3, sv2, ba2, re2);
  PAIR_UNIF(4, sv3, ba3, re3);
  PAIR_MIX(5, sv2, ba2, re2, sv3, ba3, re3);
  // q=2: n4(0,0), n5(0,+1)
  PAIR_UNIF(6, sv4, ba4, re4);
  PAIR_UNIF(7, sv5, ba5, re5);
  PAIR_MIX(8, sv4, ba4, re4, sv5, ba5, re5);
  // q=3: n6(+1,-1), n7(+1,0)
  PAIR_UNIF(9, sv6, ba6, re6);
  PAIR_UNIF(10, sv7, ba7, re7);
  PAIR_MIX(11, sv6, ba6, re6, sv7, ba7, re7);
  // n8(+1,+1)
  PAIR_UNIF(12, sv8, ba8, re8);
  PAIR_MIX(13, sv8, ba8, re8, 0, ba8, re8);

#undef PAIR_UNIF
#undef PAIR_MIX

  // D layout: col = lane&15 (=f), row = grp*4 + reg
  const int obase = pix * (NB_D * NB_F);
#pragma unroll
  for (int rr = 0; rr < 4; ++rr) {
    out[obase + (grp * 4 + rr) * NB_F + r] = acc0[rr];
    out[obase + (grp * 4 + rr + 16) * NB_F + r] = acc1[rr];
  }
}

// ---------------- fallback (self-contained) if ws is too small -------------
__global__ __launch_bounds__(256) void sconv3d_mfma(
    const float* __restrict__ img, const int* __restrict__ bp,
    const float* __restrict__ kern, const float* __restrict__ dvp,
    float* __restrict__ out, int npix) {
  __shared__ unsigned short Kb[28 * 256];
  const int tid = threadIdx.x;
  for (int idx = tid; idx < 28 * 256; idx += 256) {
    unsigned short v = 0;
    if (idx < 27 * 256) v = f2bf(kern[idx]);
    Kb[idx] = v;
  }
  __syncthreads();

  const int lane = tid & 63;
  const int grp = lane >> 4;
  const int r = lane & 15;
  const int c0 = (grp & 1) * 8;
  const int half = grp >> 1;

  short8 bfrag[14];
#pragma unroll
  for (int p = 0; p < 14; ++p) {
#pragma unroll
    for (int j = 0; j < 8; ++j) {
      const int k = 8 * grp + j;
      const int t = 2 * p + (k >> 4);
      bfrag[p][j] = (short)Kb[t * 256 + (k & 15) * 16 + r];
    }
  }

  const int pix = blockIdx.x * 4 + (tid >> 6);
  if (pix >= npix) return;
  const int b = pix / (NB_H * NB_W);
  const int rem = pix - b * (NB_H * NB_W);
  const int h = rem >> 7;
  const int w = rem & (NB_W - 1);

  const float dv = dvp[0];
  const int bpc = bp[pix];

  f32x4 acc0 = {0.f, 0.f, 0.f, 0.f};
  f32x4 acc1 = {0.f, 0.f, 0.f, 0.f};

#pragma unroll
  for (int p = 0; p < 14; ++p) {
    const int t = 2 * p + half;
    const int n = t / 3;
    const int kd = t - 3 * n;
    const int i = n / 3;
    const int j = n - 3 * i;
    const int hh = h + i - 1;
    const int ww = w + j - 1;
    const bool sv =
        (t < 27) && (hh >= 0) && (hh < NB_H) && (ww >= 0) && (ww < NB_W);
    const int hc = min(max(hh, 0), NB_H - 1);
    const int wc = min(max(ww, 0), NB_W - 1);
    const int nidx = (b * NB_H + hc) * NB_W + wc;
    const int rel = bpc - bp[nidx];
    const int base = nidx * (NB_D * NB_C);
    const int dsh = (kd - 1) + rel;

    const int ds0 = r + dsh;
    short8 a0;
    {
      float va[8];
      if (sv && (ds0 >= 0) && (ds0 < NB_D)) {
        const float4* pp = (const float4*)(img + base + ds0 * NB_C + c0);
        const float4 x = pp[0];
        const float4 y = pp[1];
        va[0] = x.x; va[1] = x.y; va[2] = x.z; va[3] = x.w;
        va[4] = y.x; va[5] = y.y; va[6] = y.z; va[7] = y.w;
      } else {
#pragma unroll
        for (int q = 0; q < 8; ++q) va[q] = dv;
      }
#pragma unroll
      for (int q = 0; q < 8; ++q) a0[q] = (short)f2bf(va[q]);
    }
    acc0 = __builtin_amdgcn_mfma_f32_16x16x32_bf16(a0, bfrag[p], acc0, 0, 0, 0);

    const int ds1 = ds0 + 16;
    short8 a1;
    {
      float va[8];
      if (sv && (ds1 >= 0) && (ds1 < NB_D)) {
        const float4* pp = (const float4*)(img + base + ds1 * NB_C + c0);
        const float4 x = pp[0];
        const float4 y = pp[1];
        va[0] = x.x; va[1] = x.y; va[2] = x.z; va[3] = x.w;
        va[4] = y.x; va[5] = y.y; va[6] = y.z; va[7] = y.w;
      } else {
#pragma unroll
        for (int q = 0; q < 8; ++q) va[q] = dv;
      }
#pragma unroll
      for (int q = 0; q < 8; ++q) a1[q] = (short)f2bf(va[q]);
    }
    acc1 = __builtin_amdgcn_mfma_f32_16x16x32_bf16(a1, bfrag[p], acc1, 0, 0, 0);
  }

  const int obase = pix * (NB_D * NB_F);
#pragma unroll
  for (int rr = 0; rr < 4; ++rr) {
    out[obase + (grp * 4 + rr) * NB_F + r] = acc0[rr];
    out[obase + (grp * 4 + rr + 16) * NB_F + r] = acc1[rr];
  }
}

extern "C" void kernel_launch(void* const* d_in, const int* in_sizes, int n_in,
                              void* d_out, int out_size, void* d_ws, size_t ws_size,
                              hipStream_t stream) {
  const float* img = (const float*)d_in[0];
  const int* bp = (const int*)d_in[1];
  const float* kern = (const float*)d_in[2];
  const float* dvp = (const float*)d_in[3];
  float* out = (float*)d_out;

  if (ws_size >= WS_NEED) {
    unsigned short* kb2 = (unsigned short*)d_ws;
    sconv3d_wprep<<<28, 256, 0, stream>>>(kern, kb2);
    sconv3d_fused<<<NPIX / 4, 256, 0, stream>>>(img, bp, kb2, dvp, out);
  } else {
    sconv3d_mfma<<<NPIX / 4, 256, 0, stream>>>(img, bp, kern, dvp, out, NPIX);
  }
}